// Round 2
// baseline (77229.669 us; speedup 1.0000x reference)
//
#include <hip/hip_runtime.h>

#define Bz   32
#define Sz   64
#define Tdec 63
#define Ez   256
#define Hz   512
#define H3z  1536
#define Vz   32000
#define NB   256   // persistent grid blocks

typedef __attribute__((ext_vector_type(4))) float floatx4;
typedef __attribute__((ext_vector_type(8))) short shortx8;

__device__ __forceinline__ unsigned short f2bf(float f) {
  unsigned x = __float_as_uint(f);
  unsigned r = (x + 0x7fffu + ((x >> 16) & 1u)) >> 16;
  return (unsigned short)r;
}

// ---------------- generic transpose: out[c][r] = in[r][c0+c] ----------------
__global__ __launch_bounds__(256)
void k_transpose(const float* __restrict__ in, int R, int Ctot, int c0,
                 float* __restrict__ out) {
  __shared__ float tile[32][33];
  int ct = blockIdx.x * 32;
  int rt = blockIdx.y * 32;
  int lx = threadIdx.x & 31, ly = threadIdx.x >> 5;
#pragma unroll
  for (int i = 0; i < 32; i += 8)
    tile[ly + i][lx] = in[(long)(rt + ly + i) * Ctot + c0 + ct + lx];
  __syncthreads();
#pragma unroll
  for (int i = 0; i < 32; i += 8)
    out[(long)(ct + ly + i) * R + rt + lx] = tile[lx][ly + i];
}

// ---- pack weights: out[(k4+k4off)*1536*4 + j*4 + q] = in[j*rs + c0 + k4*4+q]
__global__ __launch_bounds__(256)
void k_pack4(const float* __restrict__ in, int rs, int c0,
             float* __restrict__ out, int k4off) {
  int jl = threadIdx.x & 15, k4l = threadIdx.x >> 4;
  int j = blockIdx.y * 16 + jl;
  int k4 = blockIdx.x * 16 + k4l;
  float4 v = *(const float4*)(in + (long)j * rs + c0 + k4 * 4);
  *(float4*)(out + ((long)(k4 + k4off) * H3z + j) * 4) = v;
}

// -------- embed + input-GEMM with packed weights W4[k4][1536][4], K=256
// row r = t*32 + b ; tok = toks[b*64 + t]
__global__ __launch_bounds__(256)
void k_embed_gi(const int* __restrict__ toks, const float* __restrict__ emb,
                const float* __restrict__ W4, const float* __restrict__ bias,
                float* __restrict__ G) {
  __shared__ float se[16][Ez];
  int jg = blockIdx.x % 24;
  int rg = blockIdx.x / 24;
  int r0 = rg * 16;
  int tid = threadIdx.x;
  for (int c = tid; c < 16 * Ez; c += 256) {
    int rl = c >> 8;
    int k = c & 255;
    int r = r0 + rl;
    int tok = toks[(r & 31) * 64 + (r >> 5)];
    se[rl][k] = emb[(long)tok * Ez + k];
  }
  __syncthreads();
  int jj = tid & 63, rq = tid >> 6;
  int j = jg * 64 + jj;
  float a0 = 0.f, a1 = 0.f, a2 = 0.f, a3 = 0.f;
#pragma unroll 4
  for (int k4 = 0; k4 < 64; ++k4) {
    float4 w = *(const float4*)(W4 + ((long)k4 * H3z + j) * 4);
    const float* s0 = &se[rq * 4 + 0][k4 * 4];
    const float* s1 = &se[rq * 4 + 1][k4 * 4];
    const float* s2 = &se[rq * 4 + 2][k4 * 4];
    const float* s3 = &se[rq * 4 + 3][k4 * 4];
    a0 = fmaf(s0[3], w.w, fmaf(s0[2], w.z, fmaf(s0[1], w.y, fmaf(s0[0], w.x, a0))));
    a1 = fmaf(s1[3], w.w, fmaf(s1[2], w.z, fmaf(s1[1], w.y, fmaf(s1[0], w.x, a1))));
    a2 = fmaf(s2[3], w.w, fmaf(s2[2], w.z, fmaf(s2[1], w.y, fmaf(s2[0], w.x, a2))));
    a3 = fmaf(s3[3], w.w, fmaf(s3[2], w.z, fmaf(s3[1], w.y, fmaf(s3[0], w.x, a3))));
  }
  float bj = bias[j];
  G[(long)(r0 + rq * 4 + 0) * H3z + j] = a0 + bj;
  G[(long)(r0 + rq * 4 + 1) * H3z + j] = a1 + bj;
  G[(long)(r0 + rq * 4 + 2) * H3z + j] = a2 + bj;
  G[(long)(r0 + rq * 4 + 3) * H3z + j] = a3 + bj;
}

// ---------------- fp32 -> bf16 convert ----------------
__global__ void k_f2bf(const float* __restrict__ in, unsigned short* __restrict__ out, long n4) {
  long i = (long)blockIdx.x * blockDim.x + threadIdx.x;
  long stride = (long)gridDim.x * blockDim.x;
  for (; i < n4; i += stride) {
    float4 v = ((const float4*)in)[i];
    ushort4 o;
    o.x = f2bf(v.x); o.y = f2bf(v.y); o.z = f2bf(v.z); o.w = f2bf(v.w);
    ((ushort4*)out)[i] = o;
  }
}

// ================= persistent recurrence kernel =================
struct PP {
  const float* giEnc;   // [64*32][1536] incl bih0
  const float* giDec;   // [63*32][1536] incl bih0
  const float* W4e0;    // [128][1536][4]  enc whh0
  const float* W4e1;    // [256][1536][4]  enc wih1 | whh1
  const float* W4d0;    // [256][1536][4]  dec wih0-ctx | whh0
  const float* W4d1;    // [256][1536][4]  dec wih1 | whh1
  const float* enc_bhh0;
  const float* enc_bih1;
  const float* enc_bhh1;
  const float* dec_bhh0;
  const float* dec_bih1;
  const float* dec_bhh1;
  const float* wtAttn;  // [512][512] k-major
  const int* src;
  float* h0; float* h1; float* d0; float* d1; float* ctx;  // 2-slot [2][32][512]
  float* encOut;        // [32][64][512]
  float* ke;            // [32][64][512]
  unsigned short* d1ctxBf;  // [2048][1024]
  unsigned* bar;
};

__device__ __forceinline__ void gsync(unsigned* bar, unsigned target) {
  __threadfence();
  __syncthreads();
  if (threadIdx.x == 0) {
    __hip_atomic_fetch_add(bar, 1u, __ATOMIC_ACQ_REL, __HIP_MEMORY_SCOPE_AGENT);
    while (__hip_atomic_load(bar, __ATOMIC_ACQUIRE, __HIP_MEMORY_SCOPE_AGENT) < target) {
      __builtin_amdgcn_s_sleep(1);
    }
  }
  __syncthreads();
  __threadfence();
}

// GRU cell over 64 blocks: blkid in [0,64): jg=blkid&7, bg=blkid>>3
// W4 stacked: x-part k4 0..127 (if HASX), h-part next 128 k4.
template <int HASX>
__device__ __forceinline__ void gru_cell(
    int blkid, const float* __restrict__ W4,
    const float* __restrict__ gi, const float* __restrict__ bih,
    const float* __restrict__ bhh,
    const float* __restrict__ xin, const float* __restrict__ hin,
    float* __restrict__ hout, float* __restrict__ fout, long fstride,
    unsigned short* __restrict__ bfout, float* sh, float* sx) {
  int jg = blkid & 7, bg = blkid >> 3;
  int tid = threadIdx.x, jj = tid & 63, bq = tid >> 6;
  int b = bg * 4 + bq, j = jg * 64 + jj;
  for (int c = tid; c < 2048; c += 256) {
    sh[c] = hin[bg * 2048 + c];
    if (HASX) sx[c] = xin[bg * 2048 + c];
  }
  __syncthreads();
  const float4* hb = (const float4*)(sh + bq * 512);
  const float4* xb = (const float4*)(sx + bq * 512);
  const float4* Wb = (const float4*)W4 + j;
  float xr = 0.f, xz = 0.f, xn = 0.f, hr = 0.f, hz = 0.f, hn = 0.f;
  if (HASX) {
#pragma unroll 4
    for (int k4 = 0; k4 < 128; ++k4) {
      float4 v = xb[k4];
      const float4* w = Wb + (long)k4 * H3z;
      float4 wr = w[0], wz = w[512], wn = w[1024];
      xr = fmaf(v.w, wr.w, fmaf(v.z, wr.z, fmaf(v.y, wr.y, fmaf(v.x, wr.x, xr))));
      xz = fmaf(v.w, wz.w, fmaf(v.z, wz.z, fmaf(v.y, wz.y, fmaf(v.x, wz.x, xz))));
      xn = fmaf(v.w, wn.w, fmaf(v.z, wn.z, fmaf(v.y, wn.y, fmaf(v.x, wn.x, xn))));
    }
    Wb += 128L * H3z;
  }
#pragma unroll 4
  for (int k4 = 0; k4 < 128; ++k4) {
    float4 v = hb[k4];
    const float4* w = Wb + (long)k4 * H3z;
    float4 wr = w[0], wz = w[512], wn = w[1024];
    hr = fmaf(v.w, wr.w, fmaf(v.z, wr.z, fmaf(v.y, wr.y, fmaf(v.x, wr.x, hr))));
    hz = fmaf(v.w, wz.w, fmaf(v.z, wz.z, fmaf(v.y, wz.y, fmaf(v.x, wz.x, hz))));
    hn = fmaf(v.w, wn.w, fmaf(v.z, wn.z, fmaf(v.y, wn.y, fmaf(v.x, wn.x, hn))));
  }
  float gir = gi ? gi[(long)b * H3z + j] : 0.f;
  float giz = gi ? gi[(long)b * H3z + 512 + j] : 0.f;
  float gin = gi ? gi[(long)b * H3z + 1024 + j] : 0.f;
  if (bih) { gir += bih[j]; giz += bih[512 + j]; gin += bih[1024 + j]; }
  gir += xr; giz += xz; gin += xn;
  float ghr = hr + bhh[j], ghz = hz + bhh[512 + j], ghn = hn + bhh[1024 + j];
  float r = 1.f / (1.f + __expf(-(gir + ghr)));
  float z = 1.f / (1.f + __expf(-(giz + ghz)));
  float n = tanhf(gin + r * ghn);
  float hv = sh[bq * 512 + j];
  float hp = (1.f - z) * n + z * hv;
  hout[(long)b * 512 + j] = hp;
  if (fout) fout[(long)b * fstride + j] = hp;
  if (bfout) bfout[(long)b * 1024 + j] = f2bf(hp);
}

__device__ void ke_phase(int blk, const float* __restrict__ encOut,
                         const float* __restrict__ attn_wT,
                         float* __restrict__ ke, float* smem) {
  long r0 = (long)blk * 8;
  int tid = threadIdx.x;
  for (int c = tid; c < 8 * 512; c += 256) smem[c] = encOut[r0 * 512 + c];
  __syncthreads();
  int jj = tid & 63, rq = tid >> 6;
  float acc0[8] = {0, 0, 0, 0, 0, 0, 0, 0};
  float acc1[8] = {0, 0, 0, 0, 0, 0, 0, 0};
#pragma unroll 2
  for (int k = 0; k < 512; ++k) {
    float e0 = smem[(rq * 2) * 512 + k], e1 = smem[(rq * 2 + 1) * 512 + k];
#pragma unroll
    for (int jc = 0; jc < 8; ++jc) {
      float w = attn_wT[(long)k * 512 + jc * 64 + jj];
      acc0[jc] = fmaf(e0, w, acc0[jc]);
      acc1[jc] = fmaf(e1, w, acc1[jc]);
    }
  }
#pragma unroll
  for (int jc = 0; jc < 8; ++jc) {
    ke[(r0 + rq * 2) * 512 + jc * 64 + jj] = acc0[jc];
    ke[(r0 + rq * 2 + 1) * 512 + jc * 64 + jj] = acc1[jc];
  }
}

__device__ void attn_phase(int b, const float* __restrict__ d1,
                           const float* __restrict__ ke,
                           const float* __restrict__ encOut,
                           const int* __restrict__ src,
                           float* __restrict__ ctxn,
                           unsigned short* __restrict__ bfctx, float* smem) {
  float* sd = smem;
  float* sc = smem + 512;
  int tid = threadIdx.x;
  sd[tid] = d1[b * 512 + tid];
  sd[tid + 256] = d1[b * 512 + tid + 256];
  __syncthreads();
  int s = tid >> 2, q = tid & 3;
  const float4* kp = (const float4*)(ke + ((long)b * 64 + s) * 512 + q * 128);
  const float4* dp = (const float4*)(sd + q * 128);
  float p = 0.f;
#pragma unroll 8
  for (int i = 0; i < 32; ++i) {
    float4 v = kp[i];
    float4 d = dp[i];
    p += v.x * d.x + v.y * d.y + v.z * d.z + v.w * d.w;
  }
  p += __shfl_xor(p, 1);
  p += __shfl_xor(p, 2);
  if (q == 0) sc[s] = (src[b * 64 + s] == 0) ? -1e9f : p;
  __syncthreads();
  if (tid < 64) {
    float v = sc[tid];
    float m = v;
    for (int o = 32; o; o >>= 1) m = fmaxf(m, __shfl_xor(m, o));
    float e = __expf(v - m);
    float sum = e;
    for (int o = 32; o; o >>= 1) sum += __shfl_xor(sum, o);
    sc[tid] = e / sum;
  }
  __syncthreads();
  float a0 = 0.f, a1 = 0.f;
#pragma unroll 4
  for (int s2 = 0; s2 < 64; ++s2) {
    float w = sc[s2];
    const float* er = encOut + ((long)b * 64 + s2) * 512;
    a0 = fmaf(w, er[tid], a0);
    a1 = fmaf(w, er[tid + 256], a1);
  }
  ctxn[b * 512 + tid] = a0;
  ctxn[b * 512 + tid + 256] = a1;
  bfctx[b * 1024 + tid] = f2bf(a0);
  bfctx[b * 1024 + tid + 256] = f2bf(a1);
}

__global__ __launch_bounds__(256) void k_persist(PP P) {
  __shared__ float smem[4096];
  float* sh = smem;
  float* sx = smem + 2048;
  int blk = blockIdx.x;
  unsigned ph = 0;
  // ---- encoder: layer1 pipelined one step behind layer0 ----
  for (int i = 0; i < Sz + 1; ++i) {
    if (i < Sz && blk < 64) {
      gru_cell<0>(blk, P.W4e0, P.giEnc + (long)i * 49152, nullptr, P.enc_bhh0,
                  nullptr, P.h0 + (i & 1) * 16384, P.h0 + ((i + 1) & 1) * 16384,
                  nullptr, 0, nullptr, sh, sx);
    } else if (i >= 1 && blk >= 64 && blk < 128) {
      int t = i - 1;
      gru_cell<1>(blk - 64, P.W4e1, nullptr, P.enc_bih1, P.enc_bhh1,
                  P.h0 + (i & 1) * 16384, P.h1 + (t & 1) * 16384,
                  P.h1 + ((t + 1) & 1) * 16384,
                  P.encOut + (long)t * 512, (long)Sz * 512, nullptr, sh, sx);
    }
    gsync(P.bar, ++ph * NB);
  }
  // ---- ke = enc_out @ attn_w^T ----
  ke_phase(blk, P.encOut, P.wtAttn, P.ke, smem);
  gsync(P.bar, ++ph * NB);
  // ---- decoder ----
  for (int t = 0; t < Tdec; ++t) {
    int cs = t & 1, ns = (t + 1) & 1;
    const float* d0in = (t == 0) ? P.h0 : P.d0 + cs * 16384;  // enc finals in slot 0
    const float* d1in = (t == 0) ? P.h1 : P.d1 + cs * 16384;
    if (blk < 64) {
      gru_cell<1>(blk, P.W4d0, P.giDec + (long)t * 49152, nullptr, P.dec_bhh0,
                  P.ctx + cs * 16384, d0in, P.d0 + ns * 16384,
                  nullptr, 0, nullptr, sh, sx);
    }
    gsync(P.bar, ++ph * NB);
    if (blk < 64) {
      gru_cell<1>(blk, P.W4d1, nullptr, P.dec_bih1, P.dec_bhh1,
                  P.d0 + ns * 16384, d1in, P.d1 + ns * 16384,
                  nullptr, 0, P.d1ctxBf + (long)t * 32768, sh, sx);
    }
    gsync(P.bar, ++ph * NB);
    if (blk < 32) {
      attn_phase(blk, P.d1 + ns * 16384, P.ke, P.encOut, P.src,
                 P.ctx + ns * 16384, P.d1ctxBf + (long)t * 32768 + 512, smem);
    }
    gsync(P.bar, ++ph * NB);
  }
}

// ---------------- final bf16 MFMA GEMM (validated round 1) ----------------
__global__ __launch_bounds__(256)
void k_out_gemm(const unsigned short* __restrict__ A, const unsigned short* __restrict__ Bw,
                const float* __restrict__ bias, float* __restrict__ out) {
  __shared__ __align__(16) char lds[32768];
  int bid = blockIdx.x;
  int bm = bid & 15, bn = bid >> 4;
  long m0 = (long)bm * 128, n0 = (long)bn * 128;
  int tid = threadIdx.x, lane = tid & 63, wid = tid >> 6;
  int wm = wid >> 1, wn = wid & 1;
  floatx4 acc[4][4];
#pragma unroll
  for (int i = 0; i < 4; i++)
#pragma unroll
    for (int jx = 0; jx < 4; jx++) acc[i][jx] = (floatx4){0.f, 0.f, 0.f, 0.f};

  int rl = lane >> 3;
  int kb = (((lane & 7) ^ rl) << 4);

  for (int kt = 0; kt < 16; ++kt) {
    long kbyte0 = (long)kt * 128;
#pragma unroll
    for (int q = 0; q < 4; ++q) {
      int c = wid * 4 + q;
      int row = c * 8 + rl;
      const char* ga = (const char*)A + (m0 + row) * 2048 + kbyte0 + kb;
      const char* gb = (const char*)Bw + (n0 + row) * 2048 + kbyte0 + kb;
      __builtin_amdgcn_global_load_lds(
          (const __attribute__((address_space(1))) void*)ga,
          (__attribute__((address_space(3))) void*)(lds + (c << 10)), 16, 0, 0);
      __builtin_amdgcn_global_load_lds(
          (const __attribute__((address_space(1))) void*)gb,
          (__attribute__((address_space(3))) void*)(lds + 16384 + (c << 10)), 16, 0, 0);
    }
    asm volatile("s_waitcnt vmcnt(0)" ::: "memory");
    __syncthreads();
#pragma unroll
    for (int kk = 0; kk < 2; ++kk) {
      shortx8 af[4], bf[4];
#pragma unroll
      for (int f = 0; f < 4; ++f) {
        int rowA = wm * 64 + f * 16 + (lane & 15);
        int cbA = (kk * 64 + ((lane >> 4) << 4)) ^ ((rowA & 7) << 4);
        af[f] = *(const shortx8*)(lds + rowA * 128 + cbA);
        int rowB = wn * 64 + f * 16 + (lane & 15);
        int cbB = (kk * 64 + ((lane >> 4) << 4)) ^ ((rowB & 7) << 4);
        bf[f] = *(const shortx8*)(lds + 16384 + rowB * 128 + cbB);
      }
#pragma unroll
      for (int mf = 0; mf < 4; ++mf)
#pragma unroll
        for (int nf = 0; nf < 4; ++nf)
          acc[mf][nf] = __builtin_amdgcn_mfma_f32_16x16x32_bf16(af[mf], bf[nf], acc[mf][nf], 0, 0, 0);
    }
    __syncthreads();
  }
#pragma unroll
  for (int mf = 0; mf < 4; ++mf) {
#pragma unroll
    for (int nf = 0; nf < 4; ++nf) {
      long gn = n0 + wn * 64 + nf * 16 + (lane & 15);
      float bb = bias[gn];
#pragma unroll
      for (int r = 0; r < 4; ++r) {
        long gm = m0 + wm * 64 + mf * 16 + ((lane >> 4) * 4) + r;
        if (gm < (long)Tdec * Bz) {
          long t = gm >> 5, b = gm & 31;
          out[(b * Tdec + t) * (long)Vz + gn] = acc[mf][nf][r] + bb;
        }
      }
    }
  }
}

extern "C" void kernel_launch(void* const* d_in, const int* in_sizes, int n_in,
                              void* d_out, int out_size, void* d_ws, size_t ws_size,
                              hipStream_t stream) {
  const int*   src      = (const int*)d_in[0];
  const int*   tgt      = (const int*)d_in[1];
  const float* enc_emb  = (const float*)d_in[2];
  const float* enc_wih0 = (const float*)d_in[3];
  const float* enc_whh0 = (const float*)d_in[4];
  const float* enc_bih0 = (const float*)d_in[5];
  const float* enc_bhh0 = (const float*)d_in[6];
  const float* enc_wih1 = (const float*)d_in[7];
  const float* enc_whh1 = (const float*)d_in[8];
  const float* enc_bih1 = (const float*)d_in[9];
  const float* enc_bhh1 = (const float*)d_in[10];
  const float* dec_emb  = (const float*)d_in[11];
  const float* dec_wih0 = (const float*)d_in[12];
  const float* dec_whh0 = (const float*)d_in[13];
  const float* dec_bih0 = (const float*)d_in[14];
  const float* dec_bhh0 = (const float*)d_in[15];
  const float* dec_wih1 = (const float*)d_in[16];
  const float* dec_whh1 = (const float*)d_in[17];
  const float* dec_bih1 = (const float*)d_in[18];
  const float* dec_bhh1 = (const float*)d_in[19];
  const float* attn_w   = (const float*)d_in[20];
  const float* out_w    = (const float*)d_in[21];
  const float* out_b    = (const float*)d_in[22];
  float* out = (float*)d_out;

  char* ws = (char*)d_ws;
  size_t off = 0;
  auto alloc = [&](size_t bytes) -> char* {
    char* p = ws + off;
    off += (bytes + 255) & ~(size_t)255;
    return p;
  };
  float* W4embE = (float*)alloc((size_t)Ez * H3z * 4);       // enc_wih0 packed
  float* W4embD = (float*)alloc((size_t)Ez * H3z * 4);       // dec_wih0[:, :256] packed
  float* W4e0   = (float*)alloc((size_t)Hz * H3z * 4);       // enc_whh0
  float* W4e1   = (float*)alloc((size_t)2 * Hz * H3z * 4);   // enc_wih1 | enc_whh1
  float* W4d0   = (float*)alloc((size_t)2 * Hz * H3z * 4);   // dec_wih0-ctx | dec_whh0
  float* W4d1   = (float*)alloc((size_t)2 * Hz * H3z * 4);   // dec_wih1 | dec_whh1
  float* wtAttn = (float*)alloc((size_t)Hz * Hz * 4);
  float* giEnc  = (float*)alloc((size_t)Sz * Bz * H3z * 4);
  float* giDec  = (float*)alloc((size_t)Tdec * Bz * H3z * 4);
  float* encOut = (float*)alloc((size_t)Bz * Sz * Hz * 4);
  float* ke     = (float*)alloc((size_t)Bz * Sz * Hz * 4);
  float* h0buf  = (float*)alloc((size_t)2 * Bz * Hz * 4);
  float* h1buf  = (float*)alloc((size_t)2 * Bz * Hz * 4);
  float* d0buf  = (float*)alloc((size_t)2 * Bz * Hz * 4);
  float* d1buf  = (float*)alloc((size_t)2 * Bz * Hz * 4);
  float* ctxbuf = (float*)alloc((size_t)2 * Bz * Hz * 4);
  unsigned short* d1ctxBf = (unsigned short*)alloc((size_t)2048 * 1024 * 2);
  unsigned short* outwBf  = (unsigned short*)alloc((size_t)Vz * 1024 * 2);
  unsigned* bar = (unsigned*)alloc(256);
  if (off > ws_size) return;  // workspace too small -> loud failure

  dim3 tb(256);
  // weight packs: grid (K4/16, 1536/16)
  k_pack4<<<dim3(4, 96), tb, 0, stream>>>(enc_wih0, Ez, 0, W4embE, 0);
  k_pack4<<<dim3(4, 96), tb, 0, stream>>>(dec_wih0, Ez + Hz, 0, W4embD, 0);
  k_pack4<<<dim3(8, 96), tb, 0, stream>>>(enc_whh0, Hz, 0, W4e0, 0);
  k_pack4<<<dim3(8, 96), tb, 0, stream>>>(enc_wih1, Hz, 0, W4e1, 0);
  k_pack4<<<dim3(8, 96), tb, 0, stream>>>(enc_whh1, Hz, 0, W4e1, 128);
  k_pack4<<<dim3(8, 96), tb, 0, stream>>>(dec_wih0, Ez + Hz, Ez, W4d0, 0);
  k_pack4<<<dim3(8, 96), tb, 0, stream>>>(dec_whh0, Hz, 0, W4d0, 128);
  k_pack4<<<dim3(8, 96), tb, 0, stream>>>(dec_wih1, Hz, 0, W4d1, 0);
  k_pack4<<<dim3(8, 96), tb, 0, stream>>>(dec_whh1, Hz, 0, W4d1, 128);
  k_transpose<<<dim3(Hz / 32, Hz / 32), tb, 0, stream>>>(attn_w, Hz, Hz, 0, wtAttn);

  // state init
  hipMemsetAsync(h0buf, 0, (size_t)2 * Bz * Hz * 4, stream);
  hipMemsetAsync(h1buf, 0, (size_t)2 * Bz * Hz * 4, stream);
  hipMemsetAsync(ctxbuf, 0, (size_t)2 * Bz * Hz * 4, stream);
  hipMemsetAsync(d1ctxBf + (size_t)2016 * 1024, 0, (size_t)32 * 1024 * 2, stream);
  hipMemsetAsync(bar, 0, 256, stream);

  // input-side GRU contributions + bf16 weight convert
  k_embed_gi<<<24 * 128, tb, 0, stream>>>(src, enc_emb, W4embE, enc_bih0, giEnc);
  k_embed_gi<<<24 * 126, tb, 0, stream>>>(tgt, dec_emb, W4embD, dec_bih0, giDec);
  k_f2bf<<<2048, tb, 0, stream>>>(out_w, outwBf, (long)Vz * 1024 / 4);

  // persistent recurrence (cooperative; own grid barrier)
  PP pp;
  pp.giEnc = giEnc; pp.giDec = giDec;
  pp.W4e0 = W4e0; pp.W4e1 = W4e1; pp.W4d0 = W4d0; pp.W4d1 = W4d1;
  pp.enc_bhh0 = enc_bhh0; pp.enc_bih1 = enc_bih1; pp.enc_bhh1 = enc_bhh1;
  pp.dec_bhh0 = dec_bhh0; pp.dec_bih1 = dec_bih1; pp.dec_bhh1 = dec_bhh1;
  pp.wtAttn = wtAttn; pp.src = src;
  pp.h0 = h0buf; pp.h1 = h1buf; pp.d0 = d0buf; pp.d1 = d1buf; pp.ctx = ctxbuf;
  pp.encOut = encOut; pp.ke = ke; pp.d1ctxBf = d1ctxBf; pp.bar = bar;
  void* kargs[] = {&pp};
  hipError_t e = hipLaunchCooperativeKernel((const void*)k_persist, dim3(NB), dim3(256),
                                            kargs, 0, stream);
  if (e != hipSuccess) {
    k_persist<<<NB, tb, 0, stream>>>(pp);  // co-resident by capacity (256 blocks, 16KB LDS)
  }

  // batched output projection (bf16 MFMA)
  k_out_gemm<<<16 * 250, tb, 0, stream>>>(d1ctxBf, outwBf, out_b, out);
}

// Round 3
// 14259.192 us; speedup vs baseline: 5.4161x; 5.4161x over previous
//
#include <hip/hip_runtime.h>

#define Bz   32
#define Sz   64
#define Tdec 63
#define Ez   256
#define Hz   512
#define H3z  1536
#define Vz   32000
#define NB   128   // persistent grid blocks (flags barrier sized for this)

typedef __attribute__((ext_vector_type(4))) float floatx4;
typedef __attribute__((ext_vector_type(8))) short shortx8;

__device__ __forceinline__ unsigned short f2bf(float f) {
  unsigned x = __float_as_uint(f);
  unsigned r = (x + 0x7fffu + ((x >> 16) & 1u)) >> 16;
  return (unsigned short)r;
}

// ---------------- generic transpose: out[c][r] = in[r][c0+c] ----------------
__global__ __launch_bounds__(256)
void k_transpose(const float* __restrict__ in, int R, int Ctot, int c0,
                 float* __restrict__ out) {
  __shared__ float tile[32][33];
  int ct = blockIdx.x * 32;
  int rt = blockIdx.y * 32;
  int lx = threadIdx.x & 31, ly = threadIdx.x >> 5;
#pragma unroll
  for (int i = 0; i < 32; i += 8)
    tile[ly + i][lx] = in[(long)(rt + ly + i) * Ctot + c0 + ct + lx];
  __syncthreads();
#pragma unroll
  for (int i = 0; i < 32; i += 8)
    out[(long)(ct + ly + i) * R + rt + lx] = tile[lx][ly + i];
}

// ---- pack weights: out[(k4+k4off)*1536*4 + j*4 + q] = in[j*rs + c0 + k4*4+q]
__global__ __launch_bounds__(256)
void k_pack4(const float* __restrict__ in, int rs, int c0,
             float* __restrict__ out, int k4off) {
  int jl = threadIdx.x & 15, k4l = threadIdx.x >> 4;
  int j = blockIdx.y * 16 + jl;
  int k4 = blockIdx.x * 16 + k4l;
  float4 v = *(const float4*)(in + (long)j * rs + c0 + k4 * 4);
  *(float4*)(out + ((long)(k4 + k4off) * H3z + j) * 4) = v;
}

// -------- embed + input-GEMM with packed weights W4[k4][1536][4], K=256
__global__ __launch_bounds__(256)
void k_embed_gi(const int* __restrict__ toks, const float* __restrict__ emb,
                const float* __restrict__ W4, const float* __restrict__ bias,
                float* __restrict__ G) {
  __shared__ float se[16][Ez];
  int jg = blockIdx.x % 24;
  int rg = blockIdx.x / 24;
  int r0 = rg * 16;
  int tid = threadIdx.x;
  for (int c = tid; c < 16 * Ez; c += 256) {
    int rl = c >> 8;
    int k = c & 255;
    int r = r0 + rl;
    int tok = toks[(r & 31) * 64 + (r >> 5)];
    se[rl][k] = emb[(long)tok * Ez + k];
  }
  __syncthreads();
  int jj = tid & 63, rq = tid >> 6;
  int j = jg * 64 + jj;
  float a0 = 0.f, a1 = 0.f, a2 = 0.f, a3 = 0.f;
#pragma unroll 4
  for (int k4 = 0; k4 < 64; ++k4) {
    float4 w = *(const float4*)(W4 + ((long)k4 * H3z + j) * 4);
    const float* s0 = &se[rq * 4 + 0][k4 * 4];
    const float* s1 = &se[rq * 4 + 1][k4 * 4];
    const float* s2 = &se[rq * 4 + 2][k4 * 4];
    const float* s3 = &se[rq * 4 + 3][k4 * 4];
    a0 = fmaf(s0[3], w.w, fmaf(s0[2], w.z, fmaf(s0[1], w.y, fmaf(s0[0], w.x, a0))));
    a1 = fmaf(s1[3], w.w, fmaf(s1[2], w.z, fmaf(s1[1], w.y, fmaf(s1[0], w.x, a1))));
    a2 = fmaf(s2[3], w.w, fmaf(s2[2], w.z, fmaf(s2[1], w.y, fmaf(s2[0], w.x, a2))));
    a3 = fmaf(s3[3], w.w, fmaf(s3[2], w.z, fmaf(s3[1], w.y, fmaf(s3[0], w.x, a3))));
  }
  float bj = bias[j];
  G[(long)(r0 + rq * 4 + 0) * H3z + j] = a0 + bj;
  G[(long)(r0 + rq * 4 + 1) * H3z + j] = a1 + bj;
  G[(long)(r0 + rq * 4 + 2) * H3z + j] = a2 + bj;
  G[(long)(r0 + rq * 4 + 3) * H3z + j] = a3 + bj;
}

// ---------------- fp32 -> bf16 convert ----------------
__global__ void k_f2bf(const float* __restrict__ in, unsigned short* __restrict__ out, long n4) {
  long i = (long)blockIdx.x * blockDim.x + threadIdx.x;
  long stride = (long)gridDim.x * blockDim.x;
  for (; i < n4; i += stride) {
    float4 v = ((const float4*)in)[i];
    ushort4 o;
    o.x = f2bf(v.x); o.y = f2bf(v.y); o.z = f2bf(v.z); o.w = f2bf(v.w);
    ((ushort4*)out)[i] = o;
  }
}

// ================= persistent recurrence kernel =================
struct PP {
  const float* giEnc;
  const float* giDec;
  const float* W4e0;
  const float* W4e1;
  const float* W4d0;
  const float* W4d1;
  const float* enc_bhh0;
  const float* enc_bih1;
  const float* enc_bhh1;
  const float* dec_bhh0;
  const float* dec_bih1;
  const float* dec_bhh1;
  const float* wtAttn;
  const int* src;
  float* h0; float* h1; float* d0; float* d1; float* ctx;
  float* encOut;
  float* ke;
  unsigned short* d1ctxBf;
  unsigned* flags;   // [NB], monotone phase counters
};

// Grid barrier: release-store own flag, RELAXED spin on all flags (no
// per-iteration cache invalidate!), single acquire load on exit.
__device__ __forceinline__ void gsync(unsigned* flags, unsigned ph) {
  __syncthreads();  // block work done; compiler drains vmcnt before s_barrier
  int tid = threadIdx.x;
  if (tid < 64) {  // wave 0 spins
    if (tid == 0)
      __hip_atomic_store(&flags[blockIdx.x], ph, __ATOMIC_RELEASE,
                         __HIP_MEMORY_SCOPE_AGENT);
    unsigned f0, f1;
    do {
      __builtin_amdgcn_s_sleep(1);
      f0 = __hip_atomic_load(&flags[tid], __ATOMIC_RELAXED, __HIP_MEMORY_SCOPE_AGENT);
      f1 = __hip_atomic_load(&flags[tid + 64], __ATOMIC_RELAXED, __HIP_MEMORY_SCOPE_AGENT);
    } while (__any(f0 < ph || f1 < ph));   // monotone: run-ahead flags pass
    // one acquire -> one buffer_inv: discard stale L2 lines before phase reads
    (void)__hip_atomic_load(&flags[0], __ATOMIC_ACQUIRE, __HIP_MEMORY_SCOPE_AGENT);
  }
  __syncthreads();
}

// GRU cell over 64 blocks: jg=blkid&7 (j slice, == XCD id for L2 locality),
// bg=blkid>>3. W4 stacked: x-part k4 0..127 (if HASX), then h-part 128 k4.
template <int HASX>
__device__ __forceinline__ void gru_cell(
    int blkid, const float* __restrict__ W4,
    const float* __restrict__ gi, const float* __restrict__ bih,
    const float* __restrict__ bhh,
    const float* __restrict__ xin, const float* __restrict__ hin,
    float* __restrict__ hout, float* __restrict__ fout, long fstride,
    unsigned short* __restrict__ bfout, float* sh, float* sx) {
  int jg = blkid & 7, bg = blkid >> 3;
  int tid = threadIdx.x, jj = tid & 63, bq = tid >> 6;
  int b = bg * 4 + bq, j = jg * 64 + jj;
  for (int c = tid; c < 2048; c += 256) {
    sh[c] = hin[bg * 2048 + c];
    if (HASX) sx[c] = xin[bg * 2048 + c];
  }
  __syncthreads();
  const float4* hb = (const float4*)(sh + bq * 512);
  const float4* xb = (const float4*)(sx + bq * 512);
  const float4* Wb = (const float4*)W4 + j;
  float xr = 0.f, xz = 0.f, xn = 0.f, hr = 0.f, hz = 0.f, hn = 0.f;
  if (HASX) {
#pragma unroll 4
    for (int k4 = 0; k4 < 128; ++k4) {
      float4 v = xb[k4];
      const float4* w = Wb + (long)k4 * H3z;
      float4 wr = w[0], wz = w[512], wn = w[1024];
      xr = fmaf(v.w, wr.w, fmaf(v.z, wr.z, fmaf(v.y, wr.y, fmaf(v.x, wr.x, xr))));
      xz = fmaf(v.w, wz.w, fmaf(v.z, wz.z, fmaf(v.y, wz.y, fmaf(v.x, wz.x, xz))));
      xn = fmaf(v.w, wn.w, fmaf(v.z, wn.z, fmaf(v.y, wn.y, fmaf(v.x, wn.x, xn))));
    }
    Wb += 128L * H3z;
  }
#pragma unroll 4
  for (int k4 = 0; k4 < 128; ++k4) {
    float4 v = hb[k4];
    const float4* w = Wb + (long)k4 * H3z;
    float4 wr = w[0], wz = w[512], wn = w[1024];
    hr = fmaf(v.w, wr.w, fmaf(v.z, wr.z, fmaf(v.y, wr.y, fmaf(v.x, wr.x, hr))));
    hz = fmaf(v.w, wz.w, fmaf(v.z, wz.z, fmaf(v.y, wz.y, fmaf(v.x, wz.x, hz))));
    hn = fmaf(v.w, wn.w, fmaf(v.z, wn.z, fmaf(v.y, wn.y, fmaf(v.x, wn.x, hn))));
  }
  float gir = gi ? gi[(long)b * H3z + j] : 0.f;
  float giz = gi ? gi[(long)b * H3z + 512 + j] : 0.f;
  float gin = gi ? gi[(long)b * H3z + 1024 + j] : 0.f;
  if (bih) { gir += bih[j]; giz += bih[512 + j]; gin += bih[1024 + j]; }
  gir += xr; giz += xz; gin += xn;
  float ghr = hr + bhh[j], ghz = hz + bhh[512 + j], ghn = hn + bhh[1024 + j];
  float r = 1.f / (1.f + __expf(-(gir + ghr)));
  float z = 1.f / (1.f + __expf(-(giz + ghz)));
  float n = tanhf(gin + r * ghn);
  float hv = sh[bq * 512 + j];
  float hp = (1.f - z) * n + z * hv;
  hout[(long)b * 512 + j] = hp;
  if (fout) fout[(long)b * fstride + j] = hp;
  if (bfout) bfout[(long)b * 1024 + j] = f2bf(hp);
}

// ke rows r0..r0+15 on 128 blocks (rows = b*64+s)
__device__ void ke_phase(int blk, const float* __restrict__ encOut,
                         const float* __restrict__ attn_wT,
                         float* __restrict__ ke, float* smem) {
  long r0 = (long)blk * 16;
  int tid = threadIdx.x;
  for (int c = tid; c < 16 * 512; c += 256) smem[c] = encOut[r0 * 512 + c];
  __syncthreads();
  int jj = tid & 63, rq = tid >> 6;  // rq handles rows rq*4..rq*4+3
  float acc[4][8];
#pragma unroll
  for (int r = 0; r < 4; ++r)
#pragma unroll
    for (int jc = 0; jc < 8; ++jc) acc[r][jc] = 0.f;
#pragma unroll 2
  for (int k = 0; k < 512; ++k) {
    float w[8];
#pragma unroll
    for (int jc = 0; jc < 8; ++jc) w[jc] = attn_wT[(long)k * 512 + jc * 64 + jj];
#pragma unroll
    for (int r = 0; r < 4; ++r) {
      float e = smem[(rq * 4 + r) * 512 + k];  // same-address broadcast: free
#pragma unroll
      for (int jc = 0; jc < 8; ++jc) acc[r][jc] = fmaf(e, w[jc], acc[r][jc]);
    }
  }
#pragma unroll
  for (int r = 0; r < 4; ++r)
#pragma unroll
    for (int jc = 0; jc < 8; ++jc)
      ke[(r0 + rq * 4 + r) * 512 + jc * 64 + jj] = acc[r][jc];
}

__device__ void attn_phase(int b, const float* __restrict__ d1,
                           const float* __restrict__ ke,
                           const float* __restrict__ encOut,
                           const int* __restrict__ src,
                           float* __restrict__ ctxn,
                           unsigned short* __restrict__ bfctx, float* smem) {
  float* sd = smem;
  float* sc = smem + 512;
  int tid = threadIdx.x;
  sd[tid] = d1[b * 512 + tid];
  sd[tid + 256] = d1[b * 512 + tid + 256];
  __syncthreads();
  int s = tid >> 2, q = tid & 3;
  const float4* kp = (const float4*)(ke + ((long)b * 64 + s) * 512 + q * 128);
  const float4* dp = (const float4*)(sd + q * 128);
  float p = 0.f;
#pragma unroll 8
  for (int i = 0; i < 32; ++i) {
    float4 v = kp[i];
    float4 d = dp[i];
    p += v.x * d.x + v.y * d.y + v.z * d.z + v.w * d.w;
  }
  p += __shfl_xor(p, 1);
  p += __shfl_xor(p, 2);
  if (q == 0) sc[s] = (src[b * 64 + s] == 0) ? -1e9f : p;
  __syncthreads();
  if (tid < 64) {
    float v = sc[tid];
    float m = v;
    for (int o = 32; o; o >>= 1) m = fmaxf(m, __shfl_xor(m, o));
    float e = __expf(v - m);
    float sum = e;
    for (int o = 32; o; o >>= 1) sum += __shfl_xor(sum, o);
    sc[tid] = e / sum;
  }
  __syncthreads();
  float a0 = 0.f, a1 = 0.f;
#pragma unroll 4
  for (int s2 = 0; s2 < 64; ++s2) {
    float w = sc[s2];
    const float* er = encOut + ((long)b * 64 + s2) * 512;
    a0 = fmaf(w, er[tid], a0);
    a1 = fmaf(w, er[tid + 256], a1);
  }
  ctxn[b * 512 + tid] = a0;
  ctxn[b * 512 + tid + 256] = a1;
  bfctx[b * 1024 + tid] = f2bf(a0);
  bfctx[b * 1024 + tid + 256] = f2bf(a1);
}

__global__ __launch_bounds__(256) void k_persist(PP P) {
  __shared__ float smem[8192];  // 32KB: ke needs 16 rows; gru uses 16KB
  float* sh = smem;
  float* sx = smem + 2048;
  int blk = blockIdx.x;
  unsigned ph = 0;
  // ---- encoder: layer1 pipelined one step behind layer0 ----
  for (int i = 0; i < Sz + 1; ++i) {
    if (i < Sz && blk < 64) {
      gru_cell<0>(blk, P.W4e0, P.giEnc + (long)i * 49152, nullptr, P.enc_bhh0,
                  nullptr, P.h0 + (i & 1) * 16384, P.h0 + ((i + 1) & 1) * 16384,
                  nullptr, 0, nullptr, sh, sx);
    } else if (i >= 1 && blk >= 64) {
      int t = i - 1;
      gru_cell<1>(blk - 64, P.W4e1, nullptr, P.enc_bih1, P.enc_bhh1,
                  P.h0 + (i & 1) * 16384, P.h1 + (t & 1) * 16384,
                  P.h1 + ((t + 1) & 1) * 16384,
                  P.encOut + (long)t * 512, (long)Sz * 512, nullptr, sh, sx);
    }
    gsync(P.flags, ++ph);
  }
  // ---- ke = enc_out @ attn_w^T ----
  ke_phase(blk, P.encOut, P.wtAttn, P.ke, smem);
  gsync(P.flags, ++ph);
  // ---- decoder ----
  for (int t = 0; t < Tdec; ++t) {
    int cs = t & 1, ns = (t + 1) & 1;
    const float* d0in = (t == 0) ? P.h0 : P.d0 + cs * 16384;  // enc finals slot 0
    const float* d1in = (t == 0) ? P.h1 : P.d1 + cs * 16384;
    if (blk < 64) {
      gru_cell<1>(blk, P.W4d0, P.giDec + (long)t * 49152, nullptr, P.dec_bhh0,
                  P.ctx + cs * 16384, d0in, P.d0 + ns * 16384,
                  nullptr, 0, nullptr, sh, sx);
    }
    gsync(P.flags, ++ph);
    if (blk < 64) {
      gru_cell<1>(blk, P.W4d1, nullptr, P.dec_bih1, P.dec_bhh1,
                  P.d0 + ns * 16384, d1in, P.d1 + ns * 16384,
                  nullptr, 0, P.d1ctxBf + (long)t * 32768, sh, sx);
    }
    gsync(P.flags, ++ph);
    if (blk < 32) {
      attn_phase(blk, P.d1 + ns * 16384, P.ke, P.encOut, P.src,
                 P.ctx + ns * 16384, P.d1ctxBf + (long)t * 32768 + 512, smem);
    }
    gsync(P.flags, ++ph);
  }
}

// ---------------- final bf16 MFMA GEMM (validated) ----------------
__global__ __launch_bounds__(256)
void k_out_gemm(const unsigned short* __restrict__ A, const unsigned short* __restrict__ Bw,
                const float* __restrict__ bias, float* __restrict__ out) {
  __shared__ __align__(16) char lds[32768];
  int bid = blockIdx.x;
  int bm = bid & 15, bn = bid >> 4;
  long m0 = (long)bm * 128, n0 = (long)bn * 128;
  int tid = threadIdx.x, lane = tid & 63, wid = tid >> 6;
  int wm = wid >> 1, wn = wid & 1;
  floatx4 acc[4][4];
#pragma unroll
  for (int i = 0; i < 4; i++)
#pragma unroll
    for (int jx = 0; jx < 4; jx++) acc[i][jx] = (floatx4){0.f, 0.f, 0.f, 0.f};

  int rl = lane >> 3;
  int kb = (((lane & 7) ^ rl) << 4);

  for (int kt = 0; kt < 16; ++kt) {
    long kbyte0 = (long)kt * 128;
#pragma unroll
    for (int q = 0; q < 4; ++q) {
      int c = wid * 4 + q;
      int row = c * 8 + rl;
      const char* ga = (const char*)A + (m0 + row) * 2048 + kbyte0 + kb;
      const char* gb = (const char*)Bw + (n0 + row) * 2048 + kbyte0 + kb;
      __builtin_amdgcn_global_load_lds(
          (const __attribute__((address_space(1))) void*)ga,
          (__attribute__((address_space(3))) void*)(lds + (c << 10)), 16, 0, 0);
      __builtin_amdgcn_global_load_lds(
          (const __attribute__((address_space(1))) void*)gb,
          (__attribute__((address_space(3))) void*)(lds + 16384 + (c << 10)), 16, 0, 0);
    }
    asm volatile("s_waitcnt vmcnt(0)" ::: "memory");
    __syncthreads();
#pragma unroll
    for (int kk = 0; kk < 2; ++kk) {
      shortx8 af[4], bf[4];
#pragma unroll
      for (int f = 0; f < 4; ++f) {
        int rowA = wm * 64 + f * 16 + (lane & 15);
        int cbA = (kk * 64 + ((lane >> 4) << 4)) ^ ((rowA & 7) << 4);
        af[f] = *(const shortx8*)(lds + rowA * 128 + cbA);
        int rowB = wn * 64 + f * 16 + (lane & 15);
        int cbB = (kk * 64 + ((lane >> 4) << 4)) ^ ((rowB & 7) << 4);
        bf[f] = *(const shortx8*)(lds + 16384 + rowB * 128 + cbB);
      }
#pragma unroll
      for (int mf = 0; mf < 4; ++mf)
#pragma unroll
        for (int nf = 0; nf < 4; ++nf)
          acc[mf][nf] = __builtin_amdgcn_mfma_f32_16x16x32_bf16(af[mf], bf[nf], acc[mf][nf], 0, 0, 0);
    }
    __syncthreads();
  }
#pragma unroll
  for (int mf = 0; mf < 4; ++mf) {
#pragma unroll
    for (int nf = 0; nf < 4; ++nf) {
      long gn = n0 + wn * 64 + nf * 16 + (lane & 15);
      float bb = bias[gn];
#pragma unroll
      for (int r = 0; r < 4; ++r) {
        long gm = m0 + wm * 64 + mf * 16 + ((lane >> 4) * 4) + r;
        if (gm < (long)Tdec * Bz) {
          long t = gm >> 5, b = gm & 31;
          out[(b * Tdec + t) * (long)Vz + gn] = acc[mf][nf][r] + bb;
        }
      }
    }
  }
}

extern "C" void kernel_launch(void* const* d_in, const int* in_sizes, int n_in,
                              void* d_out, int out_size, void* d_ws, size_t ws_size,
                              hipStream_t stream) {
  const int*   src      = (const int*)d_in[0];
  const int*   tgt      = (const int*)d_in[1];
  const float* enc_emb  = (const float*)d_in[2];
  const float* enc_wih0 = (const float*)d_in[3];
  const float* enc_whh0 = (const float*)d_in[4];
  const float* enc_bih0 = (const float*)d_in[5];
  const float* enc_bhh0 = (const float*)d_in[6];
  const float* enc_wih1 = (const float*)d_in[7];
  const float* enc_whh1 = (const float*)d_in[8];
  const float* enc_bih1 = (const float*)d_in[9];
  const float* enc_bhh1 = (const float*)d_in[10];
  const float* dec_emb  = (const float*)d_in[11];
  const float* dec_wih0 = (const float*)d_in[12];
  const float* dec_whh0 = (const float*)d_in[13];
  const float* dec_bih0 = (const float*)d_in[14];
  const float* dec_bhh0 = (const float*)d_in[15];
  const float* dec_wih1 = (const float*)d_in[16];
  const float* dec_whh1 = (const float*)d_in[17];
  const float* dec_bih1 = (const float*)d_in[18];
  const float* dec_bhh1 = (const float*)d_in[19];
  const float* attn_w   = (const float*)d_in[20];
  const float* out_w    = (const float*)d_in[21];
  const float* out_b    = (const float*)d_in[22];
  float* out = (float*)d_out;

  char* ws = (char*)d_ws;
  size_t off = 0;
  auto alloc = [&](size_t bytes) -> char* {
    char* p = ws + off;
    off += (bytes + 255) & ~(size_t)255;
    return p;
  };
  float* W4embE = (float*)alloc((size_t)Ez * H3z * 4);
  float* W4embD = (float*)alloc((size_t)Ez * H3z * 4);
  float* W4e0   = (float*)alloc((size_t)Hz * H3z * 4);
  float* W4e1   = (float*)alloc((size_t)2 * Hz * H3z * 4);
  float* W4d0   = (float*)alloc((size_t)2 * Hz * H3z * 4);
  float* W4d1   = (float*)alloc((size_t)2 * Hz * H3z * 4);
  float* wtAttn = (float*)alloc((size_t)Hz * Hz * 4);
  float* giEnc  = (float*)alloc((size_t)Sz * Bz * H3z * 4);
  float* giDec  = (float*)alloc((size_t)Tdec * Bz * H3z * 4);
  float* encOut = (float*)alloc((size_t)Bz * Sz * Hz * 4);
  float* ke     = (float*)alloc((size_t)Bz * Sz * Hz * 4);
  float* h0buf  = (float*)alloc((size_t)2 * Bz * Hz * 4);
  float* h1buf  = (float*)alloc((size_t)2 * Bz * Hz * 4);
  float* d0buf  = (float*)alloc((size_t)2 * Bz * Hz * 4);
  float* d1buf  = (float*)alloc((size_t)2 * Bz * Hz * 4);
  float* ctxbuf = (float*)alloc((size_t)2 * Bz * Hz * 4);
  unsigned short* d1ctxBf = (unsigned short*)alloc((size_t)2048 * 1024 * 2);
  unsigned short* outwBf  = (unsigned short*)alloc((size_t)Vz * 1024 * 2);
  unsigned* flags = (unsigned*)alloc(NB * 4);
  if (off > ws_size) return;

  dim3 tb(256);
  k_pack4<<<dim3(4, 96), tb, 0, stream>>>(enc_wih0, Ez, 0, W4embE, 0);
  k_pack4<<<dim3(4, 96), tb, 0, stream>>>(dec_wih0, Ez + Hz, 0, W4embD, 0);
  k_pack4<<<dim3(8, 96), tb, 0, stream>>>(enc_whh0, Hz, 0, W4e0, 0);
  k_pack4<<<dim3(8, 96), tb, 0, stream>>>(enc_wih1, Hz, 0, W4e1, 0);
  k_pack4<<<dim3(8, 96), tb, 0, stream>>>(enc_whh1, Hz, 0, W4e1, 128);
  k_pack4<<<dim3(8, 96), tb, 0, stream>>>(dec_wih0, Ez + Hz, Ez, W4d0, 0);
  k_pack4<<<dim3(8, 96), tb, 0, stream>>>(dec_whh0, Hz, 0, W4d0, 128);
  k_pack4<<<dim3(8, 96), tb, 0, stream>>>(dec_wih1, Hz, 0, W4d1, 0);
  k_pack4<<<dim3(8, 96), tb, 0, stream>>>(dec_whh1, Hz, 0, W4d1, 128);
  k_transpose<<<dim3(Hz / 32, Hz / 32), tb, 0, stream>>>(attn_w, Hz, Hz, 0, wtAttn);

  hipMemsetAsync(h0buf, 0, (size_t)2 * Bz * Hz * 4, stream);
  hipMemsetAsync(h1buf, 0, (size_t)2 * Bz * Hz * 4, stream);
  hipMemsetAsync(ctxbuf, 0, (size_t)2 * Bz * Hz * 4, stream);
  hipMemsetAsync(d1ctxBf + (size_t)2016 * 1024, 0, (size_t)32 * 1024 * 2, stream);
  hipMemsetAsync(flags, 0, NB * 4, stream);

  k_embed_gi<<<24 * 128, tb, 0, stream>>>(src, enc_emb, W4embE, enc_bih0, giEnc);
  k_embed_gi<<<24 * 126, tb, 0, stream>>>(tgt, dec_emb, W4embD, dec_bih0, giDec);
  k_f2bf<<<2048, tb, 0, stream>>>(out_w, outwBf, (long)Vz * 1024 / 4);

  PP pp;
  pp.giEnc = giEnc; pp.giDec = giDec;
  pp.W4e0 = W4e0; pp.W4e1 = W4e1; pp.W4d0 = W4d0; pp.W4d1 = W4d1;
  pp.enc_bhh0 = enc_bhh0; pp.enc_bih1 = enc_bih1; pp.enc_bhh1 = enc_bhh1;
  pp.dec_bhh0 = dec_bhh0; pp.dec_bih1 = dec_bih1; pp.dec_bhh1 = dec_bhh1;
  pp.wtAttn = wtAttn; pp.src = src;
  pp.h0 = h0buf; pp.h1 = h1buf; pp.d0 = d0buf; pp.d1 = d1buf; pp.ctx = ctxbuf;
  pp.encOut = encOut; pp.ke = ke; pp.d1ctxBf = d1ctxBf; pp.flags = flags;
  // 128 blocks <= 256 CUs: trivially co-resident for the flags barrier
  k_persist<<<NB, tb, 0, stream>>>(pp);

  k_out_gemm<<<16 * 250, tb, 0, stream>>>(d1ctxBf, outwBf, out_b, out);
}

// Round 4
// 5890.762 us; speedup vs baseline: 13.1103x; 2.4206x over previous
//
#include <hip/hip_runtime.h>

#define Bz   32
#define Sz   64
#define Tdec 63
#define Ez   256
#define Hz   512
#define H3z  1536
#define Vz   32000
#define NB   128   // persistent grid blocks

typedef __attribute__((ext_vector_type(4))) float f32x4;
typedef __attribute__((ext_vector_type(4))) float floatx4;
typedef __attribute__((ext_vector_type(8))) short shortx8;

__device__ __forceinline__ unsigned short f2bf(float f) {
  unsigned x = __float_as_uint(f);
  unsigned r = (x + 0x7fffu + ((x >> 16) & 1u)) >> 16;
  return (unsigned short)r;
}

// ======== sc0/sc1 (MALL-coherent, L1/L2-bypass) access helpers ========
__device__ __forceinline__ void ld2_sc(const f32x4* p0, const f32x4* p1,
                                       f32x4& a, f32x4& b) {
  asm volatile(
      "global_load_dwordx4 %0, %2, off sc0 sc1\n\t"
      "global_load_dwordx4 %1, %3, off sc0 sc1\n\t"
      "s_waitcnt vmcnt(0)"
      : "=&v"(a), "=&v"(b) : "v"(p0), "v"(p1) : "memory");
}
__device__ __forceinline__ void ld4_sc(const f32x4* p0, const f32x4* p1,
                                       const f32x4* p2, const f32x4* p3,
                                       f32x4& a, f32x4& b, f32x4& c, f32x4& d) {
  asm volatile(
      "global_load_dwordx4 %0, %4, off sc0 sc1\n\t"
      "global_load_dwordx4 %1, %5, off sc0 sc1\n\t"
      "global_load_dwordx4 %2, %6, off sc0 sc1\n\t"
      "global_load_dwordx4 %3, %7, off sc0 sc1\n\t"
      "s_waitcnt vmcnt(0)"
      : "=&v"(a), "=&v"(b), "=&v"(c), "=&v"(d)
      : "v"(p0), "v"(p1), "v"(p2), "v"(p3) : "memory");
}
__device__ __forceinline__ void ld2f_sc(const float* p0, const float* p1,
                                        float& a, float& b) {
  asm volatile(
      "global_load_dword %0, %2, off sc0 sc1\n\t"
      "global_load_dword %1, %3, off sc0 sc1\n\t"
      "s_waitcnt vmcnt(0)"
      : "=&v"(a), "=&v"(b) : "v"(p0), "v"(p1) : "memory");
}
__device__ __forceinline__ void st_sc(float* p, float v) {
  asm volatile("global_store_dword %0, %1, off sc0 sc1" :: "v"(p), "v"(v) : "memory");
}
__device__ __forceinline__ void st_flag(unsigned* p, unsigned v) {
  asm volatile("global_store_dword %0, %1, off sc0 sc1" :: "v"(p), "v"(v) : "memory");
}
__device__ __forceinline__ void ld2u_sc(const unsigned* p0, const unsigned* p1,
                                        unsigned& a, unsigned& b) {
  asm volatile(
      "global_load_dword %0, %2, off sc0 sc1\n\t"
      "global_load_dword %1, %3, off sc0 sc1\n\t"
      "s_waitcnt vmcnt(0)"
      : "=&v"(a), "=&v"(b) : "v"(p0), "v"(p1) : "memory");
}

// ---------------- generic transpose: out[c][r] = in[r][c0+c] ----------------
__global__ __launch_bounds__(256)
void k_transpose(const float* __restrict__ in, int R, int Ctot, int c0,
                 float* __restrict__ out) {
  __shared__ float tile[32][33];
  int ct = blockIdx.x * 32;
  int rt = blockIdx.y * 32;
  int lx = threadIdx.x & 31, ly = threadIdx.x >> 5;
#pragma unroll
  for (int i = 0; i < 32; i += 8)
    tile[ly + i][lx] = in[(long)(rt + ly + i) * Ctot + c0 + ct + lx];
  __syncthreads();
#pragma unroll
  for (int i = 0; i < 32; i += 8)
    out[(long)(ct + ly + i) * R + rt + lx] = tile[lx][ly + i];
}

// ---- pack weights: out[(k4+k4off)*1536*4 + j*4 + q] = in[j*rs + c0 + k4*4+q]
__global__ __launch_bounds__(256)
void k_pack4(const float* __restrict__ in, int rs, int c0,
             float* __restrict__ out, int k4off) {
  int jl = threadIdx.x & 15, k4l = threadIdx.x >> 4;
  int j = blockIdx.y * 16 + jl;
  int k4 = blockIdx.x * 16 + k4l;
  float4 v = *(const float4*)(in + (long)j * rs + c0 + k4 * 4);
  *(float4*)(out + ((long)(k4 + k4off) * H3z + j) * 4) = v;
}

// -------- embed + input-GEMM with packed weights W4[k4][1536][4], K=256
__global__ __launch_bounds__(256)
void k_embed_gi(const int* __restrict__ toks, const float* __restrict__ emb,
                const float* __restrict__ W4, const float* __restrict__ bias,
                float* __restrict__ G) {
  __shared__ float se[16][Ez];
  int jg = blockIdx.x % 24;
  int rg = blockIdx.x / 24;
  int r0 = rg * 16;
  int tid = threadIdx.x;
  for (int c = tid; c < 16 * Ez; c += 256) {
    int rl = c >> 8;
    int k = c & 255;
    int r = r0 + rl;
    int tok = toks[(r & 31) * 64 + (r >> 5)];
    se[rl][k] = emb[(long)tok * Ez + k];
  }
  __syncthreads();
  int jj = tid & 63, rq = tid >> 6;
  int j = jg * 64 + jj;
  float a0 = 0.f, a1 = 0.f, a2 = 0.f, a3 = 0.f;
#pragma unroll 4
  for (int k4 = 0; k4 < 64; ++k4) {
    float4 w = *(const float4*)(W4 + ((long)k4 * H3z + j) * 4);
    const float* s0 = &se[rq * 4 + 0][k4 * 4];
    const float* s1 = &se[rq * 4 + 1][k4 * 4];
    const float* s2 = &se[rq * 4 + 2][k4 * 4];
    const float* s3 = &se[rq * 4 + 3][k4 * 4];
    a0 = fmaf(s0[3], w.w, fmaf(s0[2], w.z, fmaf(s0[1], w.y, fmaf(s0[0], w.x, a0))));
    a1 = fmaf(s1[3], w.w, fmaf(s1[2], w.z, fmaf(s1[1], w.y, fmaf(s1[0], w.x, a1))));
    a2 = fmaf(s2[3], w.w, fmaf(s2[2], w.z, fmaf(s2[1], w.y, fmaf(s2[0], w.x, a2))));
    a3 = fmaf(s3[3], w.w, fmaf(s3[2], w.z, fmaf(s3[1], w.y, fmaf(s3[0], w.x, a3))));
  }
  float bj = bias[j];
  G[(long)(r0 + rq * 4 + 0) * H3z + j] = a0 + bj;
  G[(long)(r0 + rq * 4 + 1) * H3z + j] = a1 + bj;
  G[(long)(r0 + rq * 4 + 2) * H3z + j] = a2 + bj;
  G[(long)(r0 + rq * 4 + 3) * H3z + j] = a3 + bj;
}

// ---------------- fp32 -> bf16 convert ----------------
__global__ void k_f2bf(const float* __restrict__ in, unsigned short* __restrict__ out, long n4) {
  long i = (long)blockIdx.x * blockDim.x + threadIdx.x;
  long stride = (long)gridDim.x * blockDim.x;
  for (; i < n4; i += stride) {
    float4 v = ((const float4*)in)[i];
    ushort4 o;
    o.x = f2bf(v.x); o.y = f2bf(v.y); o.z = f2bf(v.z); o.w = f2bf(v.w);
    ((ushort4*)out)[i] = o;
  }
}

// ================= persistent recurrence kernel =================
struct PP {
  const float* giEnc;
  const float* giDec;
  const float* W4e0;
  const float* W4e1;
  const float* W4d0;
  const float* W4d1;
  const float* enc_bhh0;
  const float* enc_bih1;
  const float* enc_bhh1;
  const float* dec_bhh0;
  const float* dec_bih1;
  const float* dec_bhh1;
  const float* wtAttn;
  const int* src;
  float* h0; float* h1; float* d0; float* d1; float* ctx;
  float* encOut;
  float* ke;
  unsigned short* d1ctxBf;
  unsigned* flags;   // [NB], monotone phase counters
};

// Grid barrier with NO L2 writeback/invalidate:
//  - every wave drains its sc1 data stores (vmcnt0) -> visible at MALL
//  - block stores its flag (sc1), lanes spin on sc1 flag loads
__device__ __forceinline__ void gsync(unsigned* flags, unsigned ph) {
  asm volatile("s_waitcnt vmcnt(0)" ::: "memory");  // all waves: drain sc1 stores
  __syncthreads();
  int tid = threadIdx.x;
  if (tid == 0) st_flag(&flags[blockIdx.x], ph);
  if (tid < 64) {
    const unsigned* p0 = &flags[tid];
    const unsigned* p1 = &flags[tid + 64];
    for (;;) {
      unsigned f0, f1;
      ld2u_sc(p0, p1, f0, f1);
      if (!__any(f0 < ph || f1 < ph)) break;   // monotone: run-ahead passes
      __builtin_amdgcn_s_sleep(1);
    }
  }
  __syncthreads();
}

// GRU cell over 64 blocks: jg=blkid&7, bg=blkid>>3 (4 batch rows each).
// Wave w owns K-quarter w (distinct weight slice -> no duplicate L1 traffic).
// W4 stacked: x-part k4 rows [0,128) (if HASX), then h-part 128 rows.
template <int HASX>
__device__ __forceinline__ void gru_cell(
    int blkid, const float* __restrict__ W4,
    const float* __restrict__ gi, const float* __restrict__ bih,
    const float* __restrict__ bhh,
    const float* __restrict__ xin, const float* __restrict__ hin,
    float* __restrict__ hout, float* __restrict__ fout, long fstride,
    unsigned short* __restrict__ bfout, float* smem) {
  float* sh = smem;            // [4][512]
  float* sx = smem + 2048;     // [4][512]
  float* part = smem + 4096;   // [3][4][4][64]
  const int jg = blkid & 7, bg = blkid >> 3;
  const int tid = threadIdx.x;
  // ---- stage h (and x) via sc1 16B loads ----
  {
    const f32x4* hp = (const f32x4*)(hin + bg * 2048);
    f32x4 a, b;
    if (HASX) {
      const f32x4* xp = (const f32x4*)(xin + bg * 2048);
      f32x4 c, d;
      ld4_sc(hp + tid, hp + tid + 256, xp + tid, xp + tid + 256, a, b, c, d);
      ((f32x4*)sh)[tid] = a; ((f32x4*)sh)[tid + 256] = b;
      ((f32x4*)sx)[tid] = c; ((f32x4*)sx)[tid + 256] = d;
    } else {
      ld2_sc(hp + tid, hp + tid + 256, a, b);
      ((f32x4*)sh)[tid] = a; ((f32x4*)sh)[tid + 256] = b;
    }
  }
  __syncthreads();
  // ---- wave-split dot: wave kq handles K-quarter kq, j = jg*64 + lane ----
  const int l = tid & 63;
  const int kq = tid >> 6;
  const int j = jg * 64 + l;
  const int Q = HASX ? 64 : 32;          // k4 per quarter
  const int k4lo = kq * Q;
  const f32x4* vb4;
  if (HASX) vb4 = (const f32x4*)((kq < 2) ? (sx + kq * 256) : (sh + (kq - 2) * 256));
  else      vb4 = (const f32x4*)(sh + kq * 128);
  const f32x4* Wr = (const f32x4*)W4 + (long)k4lo * H3z + j;
  float pr[4] = {0, 0, 0, 0}, pz[4] = {0, 0, 0, 0}, pn[4] = {0, 0, 0, 0};
#pragma unroll 4
  for (int kk = 0; kk < Q; ++kk) {
    f32x4 wr = Wr[0], wz = Wr[512], wn = Wr[1024];
    Wr += H3z;
#pragma unroll
    for (int b4 = 0; b4 < 4; ++b4) {
      f32x4 v = vb4[kk + b4 * 128];
      pr[b4] = fmaf(v[3], wr[3], fmaf(v[2], wr[2], fmaf(v[1], wr[1], fmaf(v[0], wr[0], pr[b4]))));
      pz[b4] = fmaf(v[3], wz[3], fmaf(v[2], wz[2], fmaf(v[1], wz[1], fmaf(v[0], wz[0], pz[b4]))));
      pn[b4] = fmaf(v[3], wn[3], fmaf(v[2], wn[2], fmaf(v[1], wn[1], fmaf(v[0], wn[0], pn[b4]))));
    }
  }
#pragma unroll
  for (int b4 = 0; b4 < 4; ++b4) {
    part[((0 * 4 + b4) * 4 + kq) * 64 + l] = pr[b4];
    part[((1 * 4 + b4) * 4 + kq) * 64 + l] = pz[b4];
    part[((2 * 4 + b4) * 4 + kq) * 64 + l] = pn[b4];
  }
  __syncthreads();
  // ---- combine + nonlinearity: thread -> (b4 = tid>>6, jc = tid&63) ----
  {
    const int b4 = tid >> 6, jc = tid & 63;
    const int b = bg * 4 + b4;
    const int jj = jg * 64 + jc;
    float sr = 0.f, sz = 0.f, snx = 0.f, snh = 0.f;
#pragma unroll
    for (int q = 0; q < 4; ++q) {
      sr += part[((0 * 4 + b4) * 4 + q) * 64 + jc];
      sz += part[((1 * 4 + b4) * 4 + q) * 64 + jc];
      float pnq = part[((2 * 4 + b4) * 4 + q) * 64 + jc];
      if (HASX && q < 2) snx += pnq; else snh += pnq;  // n-gate: keep x/h split
    }
    float gir = gi ? gi[(long)b * H3z + jj] : 0.f;
    float giz = gi ? gi[(long)b * H3z + 512 + jj] : 0.f;
    float gin = gi ? gi[(long)b * H3z + 1024 + jj] : 0.f;
    if (bih) { gir += bih[jj]; giz += bih[512 + jj]; gin += bih[1024 + jj]; }
    float rv = 1.f / (1.f + __expf(-(gir + sr + bhh[jj])));
    float zv = 1.f / (1.f + __expf(-(giz + sz + bhh[512 + jj])));
    float nv = tanhf(gin + snx + rv * (snh + bhh[1024 + jj]));
    float hv = sh[b4 * 512 + jj];
    float hp = (1.f - zv) * nv + zv * hv;
    st_sc(hout + (long)b * 512 + jj, hp);
    if (fout) st_sc(fout + (long)b * fstride + jj, hp);
    if (bfout) bfout[(long)b * 1024 + jj] = f2bf(hp);  // normal store (next dispatch)
  }
}

// ke rows r0..r0+15 on 128 blocks (rows = b*64+s); cached reads (encOut final)
__device__ void ke_phase(int blk, const float* __restrict__ encOut,
                         const float* __restrict__ attn_wT,
                         float* __restrict__ ke, float* smem) {
  long r0 = (long)blk * 16;
  int tid = threadIdx.x;
  const f32x4* ep = (const f32x4*)(encOut + r0 * 512);
  for (int c = tid; c < 2048; c += 256) ((f32x4*)smem)[c] = ep[c];
  __syncthreads();
  int jj = tid & 63, rq = tid >> 6;
  float acc[4][8];
#pragma unroll
  for (int r = 0; r < 4; ++r)
#pragma unroll
    for (int jc = 0; jc < 8; ++jc) acc[r][jc] = 0.f;
#pragma unroll 2
  for (int k = 0; k < 512; ++k) {
    float w[8];
#pragma unroll
    for (int jc = 0; jc < 8; ++jc) w[jc] = attn_wT[(long)k * 512 + jc * 64 + jj];
#pragma unroll
    for (int r = 0; r < 4; ++r) {
      float e = smem[(rq * 4 + r) * 512 + k];
#pragma unroll
      for (int jc = 0; jc < 8; ++jc) acc[r][jc] = fmaf(e, w[jc], acc[r][jc]);
    }
  }
#pragma unroll
  for (int r = 0; r < 4; ++r)
#pragma unroll
    for (int jc = 0; jc < 8; ++jc)
      st_sc(ke + (r0 + rq * 4 + r) * 512 + jc * 64 + jj, acc[r][jc]);
}

__device__ void attn_phase(int b, const float* __restrict__ d1,
                           const float* __restrict__ ke,
                           const float* __restrict__ encOut,
                           const int* __restrict__ src,
                           float* __restrict__ ctxn,
                           unsigned short* __restrict__ bfctx, float* smem) {
  float* sd = smem;
  float* sc = smem + 512;
  int tid = threadIdx.x;
  {
    float a, c;
    ld2f_sc(d1 + b * 512 + tid, d1 + b * 512 + tid + 256, a, c);
    sd[tid] = a;
    sd[tid + 256] = c;
  }
  __syncthreads();
  int s = tid >> 2, q = tid & 3;
  const float4* kp = (const float4*)(ke + ((long)b * 64 + s) * 512 + q * 128);
  const float4* dp = (const float4*)(sd + q * 128);
  float p = 0.f;
#pragma unroll 8
  for (int i = 0; i < 32; ++i) {
    float4 v = kp[i];
    float4 d = dp[i];
    p += v.x * d.x + v.y * d.y + v.z * d.z + v.w * d.w;
  }
  p += __shfl_xor(p, 1);
  p += __shfl_xor(p, 2);
  if (q == 0) sc[s] = (src[b * 64 + s] == 0) ? -1e9f : p;
  __syncthreads();
  if (tid < 64) {
    float v = sc[tid];
    float m = v;
    for (int o = 32; o; o >>= 1) m = fmaxf(m, __shfl_xor(m, o));
    float e = __expf(v - m);
    float sum = e;
    for (int o = 32; o; o >>= 1) sum += __shfl_xor(sum, o);
    sc[tid] = e / sum;
  }
  __syncthreads();
  float a0 = 0.f, a1 = 0.f;
#pragma unroll 4
  for (int s2 = 0; s2 < 64; ++s2) {
    float w = sc[s2];
    const float* er = encOut + ((long)b * 64 + s2) * 512;
    a0 = fmaf(w, er[tid], a0);
    a1 = fmaf(w, er[tid + 256], a1);
  }
  st_sc(ctxn + b * 512 + tid, a0);
  st_sc(ctxn + b * 512 + tid + 256, a1);
  bfctx[b * 1024 + tid] = f2bf(a0);
  bfctx[b * 1024 + tid + 256] = f2bf(a1);
}

__global__ __launch_bounds__(256) void k_persist(PP P) {
  __shared__ float smem[8192];  // 32KB
  int blk = blockIdx.x;
  unsigned ph = 0;
  // ---- encoder: layer1 pipelined one step behind layer0 ----
  for (int i = 0; i < Sz + 1; ++i) {
    if (i < Sz && blk < 64) {
      gru_cell<0>(blk, P.W4e0, P.giEnc + (long)i * 49152, nullptr, P.enc_bhh0,
                  nullptr, P.h0 + (i & 1) * 16384, P.h0 + ((i + 1) & 1) * 16384,
                  nullptr, 0, nullptr, smem);
    } else if (i >= 1 && blk >= 64) {
      int t = i - 1;
      gru_cell<1>(blk - 64, P.W4e1, nullptr, P.enc_bih1, P.enc_bhh1,
                  P.h0 + (i & 1) * 16384, P.h1 + (t & 1) * 16384,
                  P.h1 + ((t + 1) & 1) * 16384,
                  P.encOut + (long)t * 512, (long)Sz * 512, nullptr, smem);
    }
    gsync(P.flags, ++ph);
  }
  // ---- ke = enc_out @ attn_w^T ----
  ke_phase(blk, P.encOut, P.wtAttn, P.ke, smem);
  gsync(P.flags, ++ph);
  // ---- decoder ----
  for (int t = 0; t < Tdec; ++t) {
    int cs = t & 1, ns = (t + 1) & 1;
    const float* d0in = (t == 0) ? P.h0 : P.d0 + cs * 16384;  // enc finals slot 0
    const float* d1in = (t == 0) ? P.h1 : P.d1 + cs * 16384;
    if (blk < 64) {
      gru_cell<1>(blk, P.W4d0, P.giDec + (long)t * 49152, nullptr, P.dec_bhh0,
                  P.ctx + cs * 16384, d0in, P.d0 + ns * 16384,
                  nullptr, 0, nullptr, smem);
    }
    gsync(P.flags, ++ph);
    if (blk < 64) {
      gru_cell<1>(blk, P.W4d1, nullptr, P.dec_bih1, P.dec_bhh1,
                  P.d0 + ns * 16384, d1in, P.d1 + ns * 16384,
                  nullptr, 0, P.d1ctxBf + (long)t * 32768, smem);
    }
    gsync(P.flags, ++ph);
    if (blk < 32) {
      attn_phase(blk, P.d1 + ns * 16384, P.ke, P.encOut, P.src,
                 P.ctx + ns * 16384, P.d1ctxBf + (long)t * 32768 + 512, smem);
    }
    gsync(P.flags, ++ph);
  }
}

// ---------------- final bf16 MFMA GEMM (validated) ----------------
__global__ __launch_bounds__(256)
void k_out_gemm(const unsigned short* __restrict__ A, const unsigned short* __restrict__ Bw,
                const float* __restrict__ bias, float* __restrict__ out) {
  __shared__ __align__(16) char lds[32768];
  int bid = blockIdx.x;
  int bm = bid & 15, bn = bid >> 4;
  long m0 = (long)bm * 128, n0 = (long)bn * 128;
  int tid = threadIdx.x, lane = tid & 63, wid = tid >> 6;
  int wm = wid >> 1, wn = wid & 1;
  floatx4 acc[4][4];
#pragma unroll
  for (int i = 0; i < 4; i++)
#pragma unroll
    for (int jx = 0; jx < 4; jx++) acc[i][jx] = (floatx4){0.f, 0.f, 0.f, 0.f};

  int rl = lane >> 3;
  int kb = (((lane & 7) ^ rl) << 4);

  for (int kt = 0; kt < 16; ++kt) {
    long kbyte0 = (long)kt * 128;
#pragma unroll
    for (int q = 0; q < 4; ++q) {
      int c = wid * 4 + q;
      int row = c * 8 + rl;
      const char* ga = (const char*)A + (m0 + row) * 2048 + kbyte0 + kb;
      const char* gb = (const char*)Bw + (n0 + row) * 2048 + kbyte0 + kb;
      __builtin_amdgcn_global_load_lds(
          (const __attribute__((address_space(1))) void*)ga,
          (__attribute__((address_space(3))) void*)(lds + (c << 10)), 16, 0, 0);
      __builtin_amdgcn_global_load_lds(
          (const __attribute__((address_space(1))) void*)gb,
          (__attribute__((address_space(3))) void*)(lds + 16384 + (c << 10)), 16, 0, 0);
    }
    asm volatile("s_waitcnt vmcnt(0)" ::: "memory");
    __syncthreads();
#pragma unroll
    for (int kk = 0; kk < 2; ++kk) {
      shortx8 af[4], bf[4];
#pragma unroll
      for (int f = 0; f < 4; ++f) {
        int rowA = wm * 64 + f * 16 + (lane & 15);
        int cbA = (kk * 64 + ((lane >> 4) << 4)) ^ ((rowA & 7) << 4);
        af[f] = *(const shortx8*)(lds + rowA * 128 + cbA);
        int rowB = wn * 64 + f * 16 + (lane & 15);
        int cbB = (kk * 64 + ((lane >> 4) << 4)) ^ ((rowB & 7) << 4);
        bf[f] = *(const shortx8*)(lds + 16384 + rowB * 128 + cbB);
      }
#pragma unroll
      for (int mf = 0; mf < 4; ++mf)
#pragma unroll
        for (int nf = 0; nf < 4; ++nf)
          acc[mf][nf] = __builtin_amdgcn_mfma_f32_16x16x32_bf16(af[mf], bf[nf], acc[mf][nf], 0, 0, 0);
    }
    __syncthreads();
  }
#pragma unroll
  for (int mf = 0; mf < 4; ++mf) {
#pragma unroll
    for (int nf = 0; nf < 4; ++nf) {
      long gn = n0 + wn * 64 + nf * 16 + (lane & 15);
      float bb = bias[gn];
#pragma unroll
      for (int r = 0; r < 4; ++r) {
        long gm = m0 + wm * 64 + mf * 16 + ((lane >> 4) * 4) + r;
        if (gm < (long)Tdec * Bz) {
          long t = gm >> 5, b = gm & 31;
          out[(b * Tdec + t) * (long)Vz + gn] = acc[mf][nf][r] + bb;
        }
      }
    }
  }
}

extern "C" void kernel_launch(void* const* d_in, const int* in_sizes, int n_in,
                              void* d_out, int out_size, void* d_ws, size_t ws_size,
                              hipStream_t stream) {
  const int*   src      = (const int*)d_in[0];
  const int*   tgt      = (const int*)d_in[1];
  const float* enc_emb  = (const float*)d_in[2];
  const float* enc_wih0 = (const float*)d_in[3];
  const float* enc_whh0 = (const float*)d_in[4];
  const float* enc_bih0 = (const float*)d_in[5];
  const float* enc_bhh0 = (const float*)d_in[6];
  const float* enc_wih1 = (const float*)d_in[7];
  const float* enc_whh1 = (const float*)d_in[8];
  const float* enc_bih1 = (const float*)d_in[9];
  const float* enc_bhh1 = (const float*)d_in[10];
  const float* dec_emb  = (const float*)d_in[11];
  const float* dec_wih0 = (const float*)d_in[12];
  const float* dec_whh0 = (const float*)d_in[13];
  const float* dec_bih0 = (const float*)d_in[14];
  const float* dec_bhh0 = (const float*)d_in[15];
  const float* dec_wih1 = (const float*)d_in[16];
  const float* dec_whh1 = (const float*)d_in[17];
  const float* dec_bih1 = (const float*)d_in[18];
  const float* dec_bhh1 = (const float*)d_in[19];
  const float* attn_w   = (const float*)d_in[20];
  const float* out_w    = (const float*)d_in[21];
  const float* out_b    = (const float*)d_in[22];
  float* out = (float*)d_out;

  char* ws = (char*)d_ws;
  size_t off = 0;
  auto alloc = [&](size_t bytes) -> char* {
    char* p = ws + off;
    off += (bytes + 255) & ~(size_t)255;
    return p;
  };
  float* W4embE = (float*)alloc((size_t)Ez * H3z * 4);
  float* W4embD = (float*)alloc((size_t)Ez * H3z * 4);
  float* W4e0   = (float*)alloc((size_t)Hz * H3z * 4);
  float* W4e1   = (float*)alloc((size_t)2 * Hz * H3z * 4);
  float* W4d0   = (float*)alloc((size_t)2 * Hz * H3z * 4);
  float* W4d1   = (float*)alloc((size_t)2 * Hz * H3z * 4);
  float* wtAttn = (float*)alloc((size_t)Hz * Hz * 4);
  float* giEnc  = (float*)alloc((size_t)Sz * Bz * H3z * 4);
  float* giDec  = (float*)alloc((size_t)Tdec * Bz * H3z * 4);
  float* encOut = (float*)alloc((size_t)Bz * Sz * Hz * 4);
  float* ke     = (float*)alloc((size_t)Bz * Sz * Hz * 4);
  float* h0buf  = (float*)alloc((size_t)2 * Bz * Hz * 4);
  float* h1buf  = (float*)alloc((size_t)2 * Bz * Hz * 4);
  float* d0buf  = (float*)alloc((size_t)2 * Bz * Hz * 4);
  float* d1buf  = (float*)alloc((size_t)2 * Bz * Hz * 4);
  float* ctxbuf = (float*)alloc((size_t)2 * Bz * Hz * 4);
  unsigned short* d1ctxBf = (unsigned short*)alloc((size_t)2048 * 1024 * 2);
  unsigned short* outwBf  = (unsigned short*)alloc((size_t)Vz * 1024 * 2);
  unsigned* flags = (unsigned*)alloc(NB * 4);
  if (off > ws_size) return;

  dim3 tb(256);
  k_pack4<<<dim3(4, 96), tb, 0, stream>>>(enc_wih0, Ez, 0, W4embE, 0);
  k_pack4<<<dim3(4, 96), tb, 0, stream>>>(dec_wih0, Ez + Hz, 0, W4embD, 0);
  k_pack4<<<dim3(8, 96), tb, 0, stream>>>(enc_whh0, Hz, 0, W4e0, 0);
  k_pack4<<<dim3(8, 96), tb, 0, stream>>>(enc_wih1, Hz, 0, W4e1, 0);
  k_pack4<<<dim3(8, 96), tb, 0, stream>>>(enc_whh1, Hz, 0, W4e1, 128);
  k_pack4<<<dim3(8, 96), tb, 0, stream>>>(dec_wih0, Ez + Hz, Ez, W4d0, 0);
  k_pack4<<<dim3(8, 96), tb, 0, stream>>>(dec_whh0, Hz, 0, W4d0, 128);
  k_pack4<<<dim3(8, 96), tb, 0, stream>>>(dec_wih1, Hz, 0, W4d1, 0);
  k_pack4<<<dim3(8, 96), tb, 0, stream>>>(dec_whh1, Hz, 0, W4d1, 128);
  k_transpose<<<dim3(Hz / 32, Hz / 32), tb, 0, stream>>>(attn_w, Hz, Hz, 0, wtAttn);

  hipMemsetAsync(h0buf, 0, (size_t)2 * Bz * Hz * 4, stream);
  hipMemsetAsync(h1buf, 0, (size_t)2 * Bz * Hz * 4, stream);
  hipMemsetAsync(ctxbuf, 0, (size_t)2 * Bz * Hz * 4, stream);
  hipMemsetAsync(d1ctxBf + (size_t)2016 * 1024, 0, (size_t)32 * 1024 * 2, stream);
  hipMemsetAsync(flags, 0, NB * 4, stream);

  k_embed_gi<<<24 * 128, tb, 0, stream>>>(src, enc_emb, W4embE, enc_bih0, giEnc);
  k_embed_gi<<<24 * 126, tb, 0, stream>>>(tgt, dec_emb, W4embD, dec_bih0, giDec);
  k_f2bf<<<2048, tb, 0, stream>>>(out_w, outwBf, (long)Vz * 1024 / 4);

  PP pp;
  pp.giEnc = giEnc; pp.giDec = giDec;
  pp.W4e0 = W4e0; pp.W4e1 = W4e1; pp.W4d0 = W4d0; pp.W4d1 = W4d1;
  pp.enc_bhh0 = enc_bhh0; pp.enc_bih1 = enc_bih1; pp.enc_bhh1 = enc_bhh1;
  pp.dec_bhh0 = dec_bhh0; pp.dec_bih1 = dec_bih1; pp.dec_bhh1 = dec_bhh1;
  pp.wtAttn = wtAttn; pp.src = src;
  pp.h0 = h0buf; pp.h1 = h1buf; pp.d0 = d0buf; pp.d1 = d1buf; pp.ctx = ctxbuf;
  pp.encOut = encOut; pp.ke = ke; pp.d1ctxBf = d1ctxBf; pp.flags = flags;
  // 128 blocks <= 256 CUs: co-resident; barrier is flags-based
  k_persist<<<NB, tb, 0, stream>>>(pp);

  k_out_gemm<<<16 * 250, tb, 0, stream>>>(d1ctxBf, outwBf, out_b, out);
}